// Round 13
// baseline (38.261 us; speedup 1.0000x reference)
//
#include <hip/hip_runtime.h>
#include <stdint.h>

typedef __attribute__((ext_vector_type(4))) float  f32x4;
typedef __attribute__((ext_vector_type(8))) __bf16 bf16x8;

#define NB   32
#define CC   512
#define DD   512
#define HW   1024
#define NKS  16      // K-steps of 32

#define WAITL()  asm volatile("s_waitcnt lgkmcnt(0)" ::: "memory")
#define BARR()   do { asm volatile("" ::: "memory"); __builtin_amdgcn_s_barrier(); \
                      asm volatile("" ::: "memory"); } while (0)

// Fused softmax + batched GEMM: out[n] = softmax(atts[n]) @ images[n]
// R12 structure + three zero/low-register latency fixes:
//  1. K-loop reorder: {bv ds_reads -> writeB(next) -> loadB(kt+2) -> af+MFMA}
//     wave-private plane + same-wave DS ordering makes this safe; B flight
//     grows from ~1.0 to ~1.3 iterations with no extra registers.
//  2. phase-1 processes 2 rows concurrently (16 loads in flight, then reduce)
//  3. loadB(0/1) issued before the barrier (queue behind phase-1 loads)
__global__ __launch_bounds__(512, 2) void fused_kernel(
        const float* __restrict__ images, const float* __restrict__ atts,
        float* __restrict__ out) {
    __shared__ unsigned short lA[128][512];         // 128KB [row][chunk^row&7]
    __shared__ unsigned short lB[8][4][64][8];      // 32KB  wave/kgl planes

    const int b  = blockIdx.x;       // 0..255
    const int g  = b & 7;            // XCD
    const int q  = b >> 3;           // 0..31
    const int n  = (q & 3) * 8 + g;  // batch, n%8 == XCD
    const int t  = q >> 2;           // 0..7
    const int rt = t & 3;            // row tile 0..3 (128 rows)
    const int ct = t >> 2;           // col tile 0..1 (512 cols)

    const int tid  = threadIdx.x;
    const int lane = tid & 63;
    const int w    = tid >> 6;       // wave 0..7 -> cols ct*512 + w*64
    const int r15  = lane & 15;
    const int kgl  = lane >> 4;

    const float* gAt = atts + (size_t)n * CC * DD + (size_t)(rt * 128) * DD;
    const float* gB  = images + (size_t)n * DD * HW + ct * 512 + w * 64;
    float*       gO  = out + (size_t)n * CC * HW + (size_t)(rt * 128) * HW
                           + ct * 512 + w * 64;

    f32x4 bA[8], bB[8];              // two B reg sets (2-iter flight)

    auto loadB = [&](int kt, f32x4 (&d)[8]) {
        const float* p = gB + (size_t)(kt * 32 + kgl * 8) * HW + r15 * 4;
        #pragma unroll
        for (int j = 0; j < 8; ++j)
            d[j] = *(const f32x4*)(p + (size_t)j * HW);
    };

    // ---- phase 1: softmax fill, 32 groups x 4 rows, 2 rows in flight ----
    {
        const int grp = tid >> 4;    // 0..31
        const int l16 = tid & 15;
        #pragma unroll
        for (int s = 0; s < 4; s += 2) {
            const int row0 = grp * 4 + s;
            const int row1 = row0 + 1;
            const float* ap0 = gAt + (size_t)row0 * DD;
            const float* ap1 = gAt + (size_t)row1 * DD;
            f32x4 v0[8], v1[8];
            #pragma unroll
            for (int p = 0; p < 4; ++p) {            // chunk = p*16+l16
                v0[2*p]   = *(const f32x4*)(ap0 + (p * 16 + l16) * 8);
                v0[2*p+1] = *(const f32x4*)(ap0 + (p * 16 + l16) * 8 + 4);
            }
            #pragma unroll
            for (int p = 0; p < 4; ++p) {
                v1[2*p]   = *(const f32x4*)(ap1 + (p * 16 + l16) * 8);
                v1[2*p+1] = *(const f32x4*)(ap1 + (p * 16 + l16) * 8 + 4);
            }
            #pragma unroll
            for (int rr = 0; rr < 2; ++rr) {
                f32x4 (&v)[8] = rr ? v1 : v0;
                const int row = rr ? row1 : row0;
                float m = v[0][0];
                #pragma unroll
                for (int j = 0; j < 8; ++j)
                    #pragma unroll
                    for (int c = 0; c < 4; ++c) m = fmaxf(m, v[j][c]);
                #pragma unroll
                for (int k = 1; k < 16; k <<= 1) m = fmaxf(m, __shfl_xor(m, k, 16));
                float sum = 0.f;
                #pragma unroll
                for (int j = 0; j < 8; ++j)
                    #pragma unroll
                    for (int c = 0; c < 4; ++c) {
                        v[j][c] = __expf(v[j][c] - m);
                        sum += v[j][c];
                    }
                #pragma unroll
                for (int k = 1; k < 16; k <<= 1) sum += __shfl_xor(sum, k, 16);
                const float inv = 1.0f / sum;
                #pragma unroll
                for (int p = 0; p < 4; ++p) {        // 2-way write banks
                    bf16x8 wv;
                    #pragma unroll
                    for (int e = 0; e < 8; ++e)
                        wv[e] = (__bf16)(v[2*p + (e >> 2)][e & 3] * inv);
                    const int slot = (p * 16 + l16) ^ (row & 7);
                    *(bf16x8*)&lA[row][slot * 8] = wv;
                }
            }
        }
    }
    // pre-issue first two B tiles (land during barrier/prologue)
    loadB(0, bA);
    loadB(1, bB);
    WAITL();
    BARR();                          // the ONLY barrier in the kernel

    f32x4 acc[8][4] = {};

    // lB plane map: slot(c) = (c&3)*16 + ((c>>2) ^ ((c&3)<<2)); 2-way banks
    auto writeB = [&](const f32x4 (&d)[8]) {
        #pragma unroll
        for (int cc = 0; cc < 4; ++cc) {
            bf16x8 wv;
            #pragma unroll
            for (int j = 0; j < 8; ++j) wv[j] = (__bf16)d[j][cc];
            const int slot = cc * 16 + (r15 ^ (cc << 2));
            *(bf16x8*)&lB[w][kgl][slot][0] = wv;
        }
    };
    auto readBv = [&](bf16x8 (&bv)[4]) {
        #pragma unroll
        for (int nf = 0; nf < 4; ++nf) {
            const int c    = nf * 16 + r15;
            const int slot = (c & 3) * 16 + (((c >> 2) ^ ((c & 3) << 2)) & 15);
            bv[nf] = *(const bf16x8*)&lB[w][kgl][slot][0];
        }
    };
    auto computeA = [&](int kt, const bf16x8 (&bv)[4]) {
        bf16x8 af[8];
        #pragma unroll
        for (int m = 0; m < 8; ++m) {
            const int slot = ((kt << 2) + kgl) ^ (r15 & 7);
            af[m] = *(const bf16x8*)&lA[m * 16 + r15][slot * 8];
        }
        #pragma unroll
        for (int m = 0; m < 8; ++m)
            #pragma unroll
            for (int nf = 0; nf < 4; ++nf)
                acc[m][nf] = __builtin_amdgcn_mfma_f32_16x16x32_bf16(
                    af[m], bv[nf], acc[m][nf], 0, 0, 0);
    };

    // ---- phase 2: barrier-free K-loop ----
    writeB(bA);                      // waits bA(0) vmcnt; plane <- tile 0
    #pragma unroll
    for (int kt = 0; kt < NKS; ++kt) {
        bf16x8 bv[4];
        readBv(bv);                  // read plane (tile kt) FIRST
        if (kt + 1 < NKS) {          // then overwrite plane with tile kt+1
            if (kt & 1) {
                writeB(bA);
                if (kt + 2 < NKS) loadB(kt + 2, bB);   // refill consumed set
            } else {
                writeB(bB);
                if (kt + 2 < NKS) loadB(kt + 2, bA);
            }
        }
        computeA(kt, bv);            // af reads + 32 MFMA cover the loads
    }

    // ---- epilogue: C/D layout col=lane&15, row=(lane>>4)*4+r ----
    #pragma unroll
    for (int m = 0; m < 8; ++m)
        #pragma unroll
        for (int nf = 0; nf < 4; ++nf)
            #pragma unroll
            for (int r = 0; r < 4; ++r) {
                const int row = m * 16 + kgl * 4 + r;
                const int col = nf * 16 + r15;
                gO[(size_t)row * HW + col] = acc[m][nf][r];
            }
}

extern "C" void kernel_launch(void* const* d_in, const int* in_sizes, int n_in,
                              void* d_out, int out_size, void* d_ws, size_t ws_size,
                              hipStream_t stream) {
    const float* images = (const float*)d_in[0];
    const float* atts   = (const float*)d_in[1];
    float*       out    = (float*)d_out;

    fused_kernel<<<dim3(NB * 8), dim3(512), 0, stream>>>(images, atts, out);
}

// Round 14
// 37.356 us; speedup vs baseline: 1.0242x; 1.0242x over previous
//
#include <hip/hip_runtime.h>
#include <stdint.h>

typedef __attribute__((ext_vector_type(4))) float  f32x4;
typedef __attribute__((ext_vector_type(8))) __bf16 bf16x8;

#define NB   32
#define CC   512
#define DD   512
#define HW   1024
#define NKS  16      // K-steps of 32

#define WAITL()  asm volatile("s_waitcnt lgkmcnt(0)" ::: "memory")
#define BARR()   do { asm volatile("" ::: "memory"); __builtin_amdgcn_s_barrier(); \
                      asm volatile("" ::: "memory"); } while (0)

// Fused softmax + batched GEMM: out[n] = softmax(atts[n]) @ images[n]
// R12 structure (34.45us anchor) + ONE change: third B register set ->
// B global->reg flight deepened from ~1 to ~2 iterations. Occupancy is
// LDS-bound (160KB = 1 block/CU), so the +32 VGPR are free.
__global__ __launch_bounds__(512, 2) void fused_kernel(
        const float* __restrict__ images, const float* __restrict__ atts,
        float* __restrict__ out) {
    __shared__ unsigned short lA[128][512];         // 128KB [row][chunk^row&7]
    __shared__ unsigned short lB[8][4][64][8];      // 32KB  wave/kgl planes

    const int b  = blockIdx.x;       // 0..255
    const int g  = b & 7;            // XCD
    const int q  = b >> 3;           // 0..31
    const int n  = (q & 3) * 8 + g;  // batch, n%8 == XCD
    const int t  = q >> 2;           // 0..7
    const int rt = t & 3;            // row tile 0..3 (128 rows)
    const int ct = t >> 2;           // col tile 0..1 (512 cols)

    const int tid  = threadIdx.x;
    const int lane = tid & 63;
    const int w    = tid >> 6;       // wave 0..7 -> cols ct*512 + w*64
    const int r15  = lane & 15;
    const int kgl  = lane >> 4;

    const float* gAt = atts + (size_t)n * CC * DD + (size_t)(rt * 128) * DD;
    const float* gB  = images + (size_t)n * DD * HW + ct * 512 + w * 64;
    float*       gO  = out + (size_t)n * CC * HW + (size_t)(rt * 128) * HW
                           + ct * 512 + w * 64;

    // ---- phase 1: softmax fill. 32 groups of 16 lanes; 4 rows each ----
    {
        const int grp = tid >> 4;    // 0..31
        const int l16 = tid & 15;
        for (int s = 0; s < 4; ++s) {
            const int row = grp * 4 + s;             // 0..127
            const float* ap = gAt + (size_t)row * DD;
            f32x4 v[8];
            #pragma unroll
            for (int p = 0; p < 4; ++p) {            // chunk q = p*16+l16
                v[2*p]   = *(const f32x4*)(ap + (p * 16 + l16) * 8);
                v[2*p+1] = *(const f32x4*)(ap + (p * 16 + l16) * 8 + 4);
            }
            float m = v[0][0];
            #pragma unroll
            for (int j = 0; j < 8; ++j)
                #pragma unroll
                for (int c = 0; c < 4; ++c) m = fmaxf(m, v[j][c]);
            #pragma unroll
            for (int k = 1; k < 16; k <<= 1) m = fmaxf(m, __shfl_xor(m, k, 16));
            float sum = 0.f;
            #pragma unroll
            for (int j = 0; j < 8; ++j)
                #pragma unroll
                for (int c = 0; c < 4; ++c) {
                    v[j][c] = __expf(v[j][c] - m);
                    sum += v[j][c];
                }
            #pragma unroll
            for (int k = 1; k < 16; k <<= 1) sum += __shfl_xor(sum, k, 16);
            const float inv = 1.0f / sum;
            #pragma unroll
            for (int p = 0; p < 4; ++p) {            // 2-way write banks
                bf16x8 wv;
                #pragma unroll
                for (int e = 0; e < 8; ++e)
                    wv[e] = (__bf16)(v[2*p + (e >> 2)][e & 3] * inv);
                const int slot = (p * 16 + l16) ^ (row & 7);
                *(bf16x8*)&lA[row][slot * 8] = wv;
            }
        }
    }
    WAITL();
    BARR();                          // the ONLY barrier in the kernel

    f32x4 acc[8][4] = {};
    f32x4 bA[8], bB[8], bC[8];       // three B reg sets (2-iter flight)

    auto loadB = [&](int kt, f32x4 (&d)[8]) {
        const float* p = gB + (size_t)(kt * 32 + kgl * 8) * HW + r15 * 4;
        #pragma unroll
        for (int j = 0; j < 8; ++j)
            d[j] = *(const f32x4*)(p + (size_t)j * HW);
    };
    // lB plane map: slot(c) = (c&3)*16 + ((c>>2) ^ ((c&3)<<2)); 2-way banks
    auto writeB = [&](const f32x4 (&d)[8]) {
        #pragma unroll
        for (int cc = 0; cc < 4; ++cc) {
            bf16x8 wv;
            #pragma unroll
            for (int j = 0; j < 8; ++j) wv[j] = (__bf16)d[j][cc];
            const int slot = cc * 16 + (r15 ^ (cc << 2));
            *(bf16x8*)&lB[w][kgl][slot][0] = wv;
        }
    };
    auto compute = [&](int kt) {
        bf16x8 af[8], bv[4];
        #pragma unroll
        for (int m = 0; m < 8; ++m) {
            const int slot = ((kt << 2) + kgl) ^ (r15 & 7);
            af[m] = *(const bf16x8*)&lA[m * 16 + r15][slot * 8];
        }
        #pragma unroll
        for (int nf = 0; nf < 4; ++nf) {
            const int c    = nf * 16 + r15;
            const int slot = (c & 3) * 16 + (((c >> 2) ^ ((c & 3) << 2)) & 15);
            bv[nf] = *(const bf16x8*)&lB[w][kgl][slot][0];
        }
        #pragma unroll
        for (int m = 0; m < 8; ++m)
            #pragma unroll
            for (int nf = 0; nf < 4; ++nf)
                acc[m][nf] = __builtin_amdgcn_mfma_f32_16x16x32_bf16(
                    af[m], bv[nf], acc[m][nf], 0, 0, 0);
    };

    // ---- phase 2: barrier-free K-loop; tile t lives in reg set t%3 ----
    loadB(0, bA);
    loadB(1, bB);
    loadB(2, bC);
    writeB(bA);                      // waits bA(0) vmcnt; plane <- tile 0
    #pragma unroll
    for (int kt = 0; kt < NKS; ++kt) {
        compute(kt);                 // plane holds tile kt
        if (kt + 3 < NKS) {          // refill set kt%3 (freed last iter)
            if (kt % 3 == 0)      loadB(kt + 3, bA);
            else if (kt % 3 == 1) loadB(kt + 3, bB);
            else                  loadB(kt + 3, bC);
        }
        if (kt + 1 < NKS) {          // plane <- tile kt+1 from set (kt+1)%3
            if ((kt + 1) % 3 == 0)      writeB(bA);
            else if ((kt + 1) % 3 == 1) writeB(bB);
            else                        writeB(bC);
        }
    }

    // ---- epilogue: C/D layout col=lane&15, row=(lane>>4)*4+r ----
    #pragma unroll
    for (int m = 0; m < 8; ++m)
        #pragma unroll
        for (int nf = 0; nf < 4; ++nf)
            #pragma unroll
            for (int r = 0; r < 4; ++r) {
                const int row = m * 16 + kgl * 4 + r;
                const int col = nf * 16 + r15;
                gO[(size_t)row * HW + col] = acc[m][nf][r];
            }
}

extern "C" void kernel_launch(void* const* d_in, const int* in_sizes, int n_in,
                              void* d_out, int out_size, void* d_ws, size_t ws_size,
                              hipStream_t stream) {
    const float* images = (const float*)d_in[0];
    const float* atts   = (const float*)d_in[1];
    float*       out    = (float*)d_out;

    fused_kernel<<<dim3(NB * 8), dim3(512), 0, stream>>>(images, atts, out);
}